// Round 1
// baseline (598.763 us; speedup 1.0000x reference)
//
#include <hip/hip_runtime.h>

#define HDIM 2048
#define HH (HDIM * HDIM)          // 4,194,304
#define NIDX 2000000
#define BINS 256

// workspace layout
//   [0, 8)            double accumulator
//   [256, 256+6144)   uint hist[6][256]  (dst: ch0..2, then ref: ch0..2)
//   [8192, 8192+3072) float tables[3][256]
//   [16384, 16384+524288) scatter bitmap, 1 bit per pixel
#define ACC_OFF   0
#define HIST_OFF  256
#define TAB_OFF   8192
#define BITS_OFF  16384
#define WS_ZERO_BYTES (BITS_OFF + HH / 8)

__global__ __launch_bounds__(256) void hist_kernel(
    const float* __restrict__ ref, const float* __restrict__ tgt,
    const float* __restrict__ msrc, const float* __restrict__ mtar,
    const int* __restrict__ i0, const int* __restrict__ i1,
    const int* __restrict__ i2, const int* __restrict__ i3,
    unsigned* __restrict__ hist, unsigned* __restrict__ bits)
{
    __shared__ unsigned lhist[6 * BINS];
    for (int t = threadIdx.x; t < 6 * BINS; t += 256) lhist[t] = 0;
    __syncthreads();

    const int stride = gridDim.x * 256;
    for (int n = blockIdx.x * 256 + threadIdx.x; n < NIDX; n += stride) {
        const int a = i0[n], b = i1[n], c = i2[n], d = i3[n];
        const int pd = a * HDIM + b;   // dst position (ref_masked gather + scatter target)
        const int pr = c * HDIM + d;   // ref position (target_masked gather)
        const float ms = msrc[pd];
        const float mt = mtar[pr];
        atomicOr(&bits[pd >> 5], 1u << (pd & 31));
#pragma unroll
        for (int ch = 0; ch < 3; ch++) {
            // match reference op order: ((x+1)*0.5)*255, then * mask
            float vd = ((ref[ch * HH + pd] + 1.0f) * 0.5f) * 255.0f * ms;
            float vr = ((tgt[ch * HH + pr] + 1.0f) * 0.5f) * 255.0f * mt;
            int bd = (int)fminf(fmaxf(floorf(vd), 0.0f), 255.0f);
            int br = (int)fminf(fmaxf(floorf(vr), 0.0f), 255.0f);
            atomicAdd(&lhist[ch * BINS + bd], 1u);
            atomicAdd(&lhist[3 * BINS + ch * BINS + br], 1u);
        }
    }
    __syncthreads();
    for (int t = threadIdx.x; t < 6 * BINS; t += 256) {
        unsigned v = lhist[t];
        if (v) atomicAdd(&hist[t], v);
    }
}

__global__ __launch_bounds__(256) void table_kernel(
    const unsigned* __restrict__ hist, float* __restrict__ tables)
{
    __shared__ float cdf_d[3][BINS];
    __shared__ float cdf_r[3][BINS];
    __shared__ unsigned h[6 * BINS];
    const int t = threadIdx.x;
    for (int k = t; k < 6 * BINS; k += 256) h[k] = hist[k];
    __syncthreads();
    if (t < 6) {
        unsigned cum = 0;
        for (int b = 0; b < BINS; b++) {
            cum += h[t * BINS + b];
            float v = (float)cum / 2000000.0f;   // exact ints < 2^24; single-rounded divide
            if (t < 3) cdf_d[t][b] = v;
            else       cdf_r[t - 3][b] = v;
        }
    }
    __syncthreads();
    for (int c = 0; c < 3; c++) {
        float out;
        if (t == 0)             out = 0.0f;
        else if (t == BINS - 1) out = 255.0f;
        else {
            const float v = cdf_d[c][t];
            int jf = -1;
            for (int j = 0; j < BINS - 1; j++) {
                if (cdf_r[c][j] <= v && v <= cdf_r[c][j + 1]) { jf = j; break; }
            }
            out = (jf >= 0) ? (float)(jf + 1) : (float)t;
        }
        tables[c * BINS + t] = out;
    }
}

__global__ __launch_bounds__(256) void loss_kernel(
    const float* __restrict__ inp, const float* __restrict__ ref,
    const float* __restrict__ msrc, const float* __restrict__ tables_g,
    const unsigned* __restrict__ bits, double* __restrict__ acc)
{
    __shared__ float tab[3 * BINS];
    for (int t = threadIdx.x; t < 3 * BINS; t += 256) tab[t] = tables_g[t];
    __syncthreads();

    double local = 0.0;
    const int ngroups = 3 * HH / 4;   // float4 groups
    const int stride = gridDim.x * 256;
    for (int g = blockIdx.x * 256 + threadIdx.x; g < ngroups; g += stride) {
        const int c = g / (HH / 4);
        const int p = (g - c * (HH / 4)) * 4;
        const float4 rv = *(const float4*)(ref + c * HH + p);
        const float4 iv = *(const float4*)(inp + c * HH + p);
        const float4 mv = *(const float4*)(msrc + p);
        const unsigned w = bits[p >> 5] >> (p & 31);  // p % 4 == 0, 4 bits never cross a word
        const float r[4] = {rv.x, rv.y, rv.z, rv.w};
        const float x[4] = {iv.x, iv.y, iv.z, iv.w};
        const float m[4] = {mv.x, mv.y, mv.z, mv.w};
        float s = 0.0f;
#pragma unroll
        for (int k = 0; k < 4; k++) {
            const float mm = m[k];
            const float refm = ((r[k] + 1.0f) * 0.5f) * 255.0f * mm;   // ref_masked
            const float inpm = ((x[k] + 1.0f) * 0.5f) * 255.0f * mm;   // input_masked
            float matchv;
            if ((w >> k) & 1u) {
                const int b = (int)fminf(fmaxf(refm, 0.0f), 255.0f);
                matchv = tab[c * BINS + b];
            } else {
                matchv = refm;
            }
            const float d = inpm - matchv * mm;
            s += d * d;
        }
        local += (double)s;
    }

    __shared__ double red[256];
    red[threadIdx.x] = local;
    __syncthreads();
    for (int s2 = 128; s2 > 0; s2 >>= 1) {
        if (threadIdx.x < s2) red[threadIdx.x] += red[threadIdx.x + s2];
        __syncthreads();
    }
    if (threadIdx.x == 0) atomicAdd(acc, red[0]);
}

__global__ void finalize_kernel(const double* __restrict__ acc, float* __restrict__ out)
{
    out[0] = (float)(acc[0] / (double)(3 * HH));
}

extern "C" void kernel_launch(void* const* d_in, const int* in_sizes, int n_in,
                              void* d_out, int out_size, void* d_ws, size_t ws_size,
                              hipStream_t stream)
{
    const float* input_data  = (const float*)d_in[0];
    const float* target_data = (const float*)d_in[1];
    const float* mask_src    = (const float*)d_in[2];
    const float* mask_tar    = (const float*)d_in[3];
    const int*   i0          = (const int*)d_in[4];
    const int*   i1          = (const int*)d_in[5];
    const int*   i2          = (const int*)d_in[6];
    const int*   i3          = (const int*)d_in[7];
    const float* ref_data    = (const float*)d_in[8];
    float* out = (float*)d_out;

    char* ws = (char*)d_ws;
    double*   acc    = (double*)(ws + ACC_OFF);
    unsigned* hist   = (unsigned*)(ws + HIST_OFF);
    float*    tables = (float*)(ws + TAB_OFF);
    unsigned* bits   = (unsigned*)(ws + BITS_OFF);

    hipMemsetAsync(ws, 0, WS_ZERO_BYTES, stream);
    hist_kernel<<<512, 256, 0, stream>>>(ref_data, target_data, mask_src, mask_tar,
                                         i0, i1, i2, i3, hist, bits);
    table_kernel<<<1, 256, 0, stream>>>(hist, tables);
    loss_kernel<<<4096, 256, 0, stream>>>(input_data, ref_data, mask_src, tables, bits, acc);
    finalize_kernel<<<1, 1, 0, stream>>>(acc, out);
}

// Round 2
// 456.668 us; speedup vs baseline: 1.3112x; 1.3112x over previous
//
#include <hip/hip_runtime.h>

#define HDIM 2048
#define HH (HDIM * HDIM)          // 4,194,304
#define NIDX 2000000
#define BINS 256
#define NCOPY 16                  // spread copies of the global histogram

// workspace layout (bytes)
#define ACC_OFF      0                      // double accumulator (8B)
#define HIST_OFF     256                    // uint hist[NCOPY][6][256] = 96 KB
#define TAB_OFF      102400                 // float tables[3][256] = 3 KB
#define BITS_OFF     131072                 // scatter bitmap, HH/8 = 512 KB
#define PACKED_D_OFF 1048576                // uint packed_d[HH] = 16 MB
#define PACKED_R_OFF 17825792               // uint packed_r[HH] = 16 MB
#define WS_ZERO_BYTES (BITS_OFF + HH / 8)   // zero acc+hist+tables+bits in one memset

// Pack 3 channel bins (mask folded in: v*0 -> bin 0) into one uint per pixel.
__global__ __launch_bounds__(256) void pack_kernel(
    const float* __restrict__ ref, const float* __restrict__ tgt,
    const float* __restrict__ msrc, const float* __restrict__ mtar,
    unsigned* __restrict__ packed_d, unsigned* __restrict__ packed_r)
{
    const int stride = gridDim.x * 256;
    for (int g = blockIdx.x * 256 + threadIdx.x; g < HH / 4; g += stride) {
        const int p = g * 4;
        const float4 ms4 = *(const float4*)(msrc + p);
        const float4 mt4 = *(const float4*)(mtar + p);
        const float ms[4] = {ms4.x, ms4.y, ms4.z, ms4.w};
        const float mt[4] = {mt4.x, mt4.y, mt4.z, mt4.w};
        unsigned od[4] = {0, 0, 0, 0}, orr[4] = {0, 0, 0, 0};
#pragma unroll
        for (int c = 0; c < 3; c++) {
            const float4 rv = *(const float4*)(ref + c * HH + p);
            const float4 tv = *(const float4*)(tgt + c * HH + p);
            const float r[4] = {rv.x, rv.y, rv.z, rv.w};
            const float t[4] = {tv.x, tv.y, tv.z, tv.w};
#pragma unroll
            for (int k = 0; k < 4; k++) {
                // match reference op order: ((x+1)*0.5)*255, then * mask
                const float vd = ((r[k] + 1.0f) * 0.5f) * 255.0f * ms[k];
                const float vr = ((t[k] + 1.0f) * 0.5f) * 255.0f * mt[k];
                const unsigned bd = (unsigned)(int)fminf(fmaxf(floorf(vd), 0.0f), 255.0f);
                const unsigned br = (unsigned)(int)fminf(fmaxf(floorf(vr), 0.0f), 255.0f);
                od[k]  |= bd << (8 * c);
                orr[k] |= br << (8 * c);
            }
        }
        *(uint4*)(packed_d + p) = make_uint4(od[0], od[1], od[2], od[3]);
        *(uint4*)(packed_r + p) = make_uint4(orr[0], orr[1], orr[2], orr[3]);
    }
}

__global__ __launch_bounds__(256) void hist_kernel(
    const unsigned* __restrict__ packed_d, const unsigned* __restrict__ packed_r,
    const int* __restrict__ i0, const int* __restrict__ i1,
    const int* __restrict__ i2, const int* __restrict__ i3,
    unsigned* __restrict__ hist, unsigned* __restrict__ bits)
{
    __shared__ unsigned lhist[6 * BINS];
    for (int t = threadIdx.x; t < 6 * BINS; t += 256) lhist[t] = 0;
    __syncthreads();

    // process index PAIRS: int2 coalesced index loads, 4 outstanding gathers/iter
    const int stride = gridDim.x * 256;
    for (int n2 = blockIdx.x * 256 + threadIdx.x; n2 < NIDX / 2; n2 += stride) {
        const int2 a = *(const int2*)(i0 + 2 * n2);
        const int2 b = *(const int2*)(i1 + 2 * n2);
        const int2 c = *(const int2*)(i2 + 2 * n2);
        const int2 d = *(const int2*)(i3 + 2 * n2);
        const int pd0 = a.x * HDIM + b.x, pd1 = a.y * HDIM + b.y;
        const int pr0 = c.x * HDIM + d.x, pr1 = c.y * HDIM + d.y;
        const unsigned wd0 = packed_d[pd0];
        const unsigned wd1 = packed_d[pd1];
        const unsigned wr0 = packed_r[pr0];
        const unsigned wr1 = packed_r[pr1];
        atomicOr(&bits[pd0 >> 5], 1u << (pd0 & 31));
        atomicOr(&bits[pd1 >> 5], 1u << (pd1 & 31));
        atomicAdd(&lhist[              (wd0       & 255u)], 1u);
        atomicAdd(&lhist[1 * BINS + ((wd0 >> 8)  & 255u)], 1u);
        atomicAdd(&lhist[2 * BINS + ((wd0 >> 16) & 255u)], 1u);
        atomicAdd(&lhist[              (wd1       & 255u)], 1u);
        atomicAdd(&lhist[1 * BINS + ((wd1 >> 8)  & 255u)], 1u);
        atomicAdd(&lhist[2 * BINS + ((wd1 >> 16) & 255u)], 1u);
        atomicAdd(&lhist[3 * BINS + ((wr0)       & 255u)], 1u);
        atomicAdd(&lhist[4 * BINS + ((wr0 >> 8)  & 255u)], 1u);
        atomicAdd(&lhist[5 * BINS + ((wr0 >> 16) & 255u)], 1u);
        atomicAdd(&lhist[3 * BINS + ((wr1)       & 255u)], 1u);
        atomicAdd(&lhist[4 * BINS + ((wr1 >> 8)  & 255u)], 1u);
        atomicAdd(&lhist[5 * BINS + ((wr1 >> 16) & 255u)], 1u);
    }
    __syncthreads();
    unsigned* h = hist + (blockIdx.x & (NCOPY - 1)) * (6 * BINS);
    for (int t = threadIdx.x; t < 6 * BINS; t += 256) {
        const unsigned v = lhist[t];
        if (v) atomicAdd(&h[t], v);
    }
}

__global__ __launch_bounds__(256) void table_kernel(
    const unsigned* __restrict__ hist, float* __restrict__ tables)
{
    __shared__ float cdf_d[3][BINS];
    __shared__ float cdf_r[3][BINS];
    __shared__ unsigned h[6 * BINS];
    const int t = threadIdx.x;
    for (int k = t; k < 6 * BINS; k += 256) {
        unsigned s = 0;
#pragma unroll
        for (int cp = 0; cp < NCOPY; cp++) s += hist[cp * (6 * BINS) + k];
        h[k] = s;
    }
    __syncthreads();
    if (t < 6) {
        unsigned cum = 0;
        for (int b = 0; b < BINS; b++) {
            cum += h[t * BINS + b];
            const float v = (float)cum / 2000000.0f;   // exact ints < 2^24, single rounding
            if (t < 3) cdf_d[t][b] = v;
            else       cdf_r[t - 3][b] = v;
        }
    }
    __syncthreads();
    for (int c = 0; c < 3; c++) {
        float out;
        if (t == 0)             out = 0.0f;
        else if (t == BINS - 1) out = 255.0f;
        else {
            const float v = cdf_d[c][t];
            int jf = -1;
            for (int j = 0; j < BINS - 1; j++) {
                if (cdf_r[c][j] <= v && v <= cdf_r[c][j + 1]) { jf = j; break; }
            }
            out = (jf >= 0) ? (float)(jf + 1) : (float)t;
        }
        tables[c * BINS + t] = out;
    }
}

__global__ __launch_bounds__(256) void loss_kernel(
    const float* __restrict__ inp, const float* __restrict__ ref,
    const float* __restrict__ msrc, const float* __restrict__ tables_g,
    const unsigned* __restrict__ bits, double* __restrict__ acc)
{
    __shared__ float tab[3 * BINS];
    for (int t = threadIdx.x; t < 3 * BINS; t += 256) tab[t] = tables_g[t];
    __syncthreads();

    double local = 0.0;
    const int ngroups = 3 * HH / 4;   // float4 groups
    const int stride = gridDim.x * 256;
    for (int g = blockIdx.x * 256 + threadIdx.x; g < ngroups; g += stride) {
        const int c = g / (HH / 4);
        const int p = (g - c * (HH / 4)) * 4;
        const float4 rv = *(const float4*)(ref + c * HH + p);
        const float4 iv = *(const float4*)(inp + c * HH + p);
        const float4 mv = *(const float4*)(msrc + p);
        const unsigned w = bits[p >> 5] >> (p & 31);  // p % 4 == 0, bits never cross a word
        const float r[4] = {rv.x, rv.y, rv.z, rv.w};
        const float x[4] = {iv.x, iv.y, iv.z, iv.w};
        const float m[4] = {mv.x, mv.y, mv.z, mv.w};
        float s = 0.0f;
#pragma unroll
        for (int k = 0; k < 4; k++) {
            const float mm = m[k];
            const float refm = ((r[k] + 1.0f) * 0.5f) * 255.0f * mm;   // ref_masked
            const float inpm = ((x[k] + 1.0f) * 0.5f) * 255.0f * mm;   // input_masked
            float matchv;
            if ((w >> k) & 1u) {
                const int bidx = (int)fminf(fmaxf(refm, 0.0f), 255.0f); // clip then trunc (ref semantics)
                matchv = tab[c * BINS + bidx];
            } else {
                matchv = refm;
            }
            const float d = inpm - matchv * mm;
            s += d * d;
        }
        local += (double)s;
    }

    __shared__ double red[256];
    red[threadIdx.x] = local;
    __syncthreads();
    for (int s2 = 128; s2 > 0; s2 >>= 1) {
        if (threadIdx.x < s2) red[threadIdx.x] += red[threadIdx.x + s2];
        __syncthreads();
    }
    if (threadIdx.x == 0) atomicAdd(acc, red[0]);
}

__global__ void finalize_kernel(const double* __restrict__ acc, float* __restrict__ out)
{
    out[0] = (float)(acc[0] / (double)(3 * HH));
}

extern "C" void kernel_launch(void* const* d_in, const int* in_sizes, int n_in,
                              void* d_out, int out_size, void* d_ws, size_t ws_size,
                              hipStream_t stream)
{
    const float* input_data  = (const float*)d_in[0];
    const float* target_data = (const float*)d_in[1];
    const float* mask_src    = (const float*)d_in[2];
    const float* mask_tar    = (const float*)d_in[3];
    const int*   i0          = (const int*)d_in[4];
    const int*   i1          = (const int*)d_in[5];
    const int*   i2          = (const int*)d_in[6];
    const int*   i3          = (const int*)d_in[7];
    const float* ref_data    = (const float*)d_in[8];
    float* out = (float*)d_out;

    char* ws = (char*)d_ws;
    double*   acc      = (double*)(ws + ACC_OFF);
    unsigned* hist     = (unsigned*)(ws + HIST_OFF);
    float*    tables   = (float*)(ws + TAB_OFF);
    unsigned* bits     = (unsigned*)(ws + BITS_OFF);
    unsigned* packed_d = (unsigned*)(ws + PACKED_D_OFF);
    unsigned* packed_r = (unsigned*)(ws + PACKED_R_OFF);

    hipMemsetAsync(ws, 0, WS_ZERO_BYTES, stream);
    pack_kernel<<<2048, 256, 0, stream>>>(ref_data, target_data, mask_src, mask_tar,
                                          packed_d, packed_r);
    hist_kernel<<<1024, 256, 0, stream>>>(packed_d, packed_r, i0, i1, i2, i3, hist, bits);
    table_kernel<<<1, 256, 0, stream>>>(hist, tables);
    loss_kernel<<<4096, 256, 0, stream>>>(input_data, ref_data, mask_src, tables, bits, acc);
    finalize_kernel<<<1, 1, 0, stream>>>(acc, out);
}

// Round 3
// 372.035 us; speedup vs baseline: 1.6094x; 1.2275x over previous
//
#include <hip/hip_runtime.h>

#define HDIM 2048
#define HH (HDIM * HDIM)          // 4,194,304
#define NIDX 2000000
#define BINS 256
#define NCOPY 16                  // spread copies of the global histogram

// workspace layout (bytes)
#define ACC_OFF      0                      // double accumulator (8B)
#define HIST_OFF     256                    // uint hist[NCOPY][6][256] = 96 KB
#define TAB_OFF      102400                 // float tables[3][256] = 3 KB
#define BITS_OFF     131072                 // scatter bitmap, HH/8 = 512 KB
#define PACKED_D_OFF 1048576                // uint packed_d[HH] = 16 MB
#define PACKED_R_OFF 17825792               // uint packed_r[HH] = 16 MB
#define WS_ZERO_BYTES (BITS_OFF + HH / 8)   // zero acc+hist+tables+bits in one memset

// Pack 3 channel bins (mask folded in: v*0 -> bin 0) into one uint per pixel.
__global__ __launch_bounds__(256) void pack_kernel(
    const float* __restrict__ ref, const float* __restrict__ tgt,
    const float* __restrict__ msrc, const float* __restrict__ mtar,
    unsigned* __restrict__ packed_d, unsigned* __restrict__ packed_r)
{
    const int stride = gridDim.x * 256;
    for (int g = blockIdx.x * 256 + threadIdx.x; g < HH / 4; g += stride) {
        const int p = g * 4;
        const float4 ms4 = *(const float4*)(msrc + p);
        const float4 mt4 = *(const float4*)(mtar + p);
        const float ms[4] = {ms4.x, ms4.y, ms4.z, ms4.w};
        const float mt[4] = {mt4.x, mt4.y, mt4.z, mt4.w};
        unsigned od[4] = {0, 0, 0, 0}, orr[4] = {0, 0, 0, 0};
#pragma unroll
        for (int c = 0; c < 3; c++) {
            const float4 rv = *(const float4*)(ref + c * HH + p);
            const float4 tv = *(const float4*)(tgt + c * HH + p);
            const float r[4] = {rv.x, rv.y, rv.z, rv.w};
            const float t[4] = {tv.x, tv.y, tv.z, tv.w};
#pragma unroll
            for (int k = 0; k < 4; k++) {
                // match reference op order: ((x+1)*0.5)*255, then * mask
                const float vd = ((r[k] + 1.0f) * 0.5f) * 255.0f * ms[k];
                const float vr = ((t[k] + 1.0f) * 0.5f) * 255.0f * mt[k];
                const unsigned bd = (unsigned)(int)fminf(fmaxf(floorf(vd), 0.0f), 255.0f);
                const unsigned br = (unsigned)(int)fminf(fmaxf(floorf(vr), 0.0f), 255.0f);
                od[k]  |= bd << (8 * c);
                orr[k] |= br << (8 * c);
            }
        }
        *(uint4*)(packed_d + p) = make_uint4(od[0], od[1], od[2], od[3]);
        *(uint4*)(packed_r + p) = make_uint4(orr[0], orr[1], orr[2], orr[3]);
    }
}

__global__ __launch_bounds__(256) void hist_kernel(
    const unsigned* __restrict__ packed_d, const unsigned* __restrict__ packed_r,
    const int* __restrict__ i0, const int* __restrict__ i1,
    const int* __restrict__ i2, const int* __restrict__ i3,
    unsigned* __restrict__ hist, unsigned* __restrict__ bits)
{
    __shared__ unsigned lhist[6 * BINS];
    for (int t = threadIdx.x; t < 6 * BINS; t += 256) lhist[t] = 0;
    __syncthreads();

    // process index PAIRS: int2 coalesced index loads, 4 outstanding gathers/iter
    const int stride = gridDim.x * 256;
    for (int n2 = blockIdx.x * 256 + threadIdx.x; n2 < NIDX / 2; n2 += stride) {
        const int2 a = *(const int2*)(i0 + 2 * n2);
        const int2 b = *(const int2*)(i1 + 2 * n2);
        const int2 c = *(const int2*)(i2 + 2 * n2);
        const int2 d = *(const int2*)(i3 + 2 * n2);
        const int pd0 = a.x * HDIM + b.x, pd1 = a.y * HDIM + b.y;
        const int pr0 = c.x * HDIM + d.x, pr1 = c.y * HDIM + d.y;
        const unsigned wd0 = packed_d[pd0];
        const unsigned wd1 = packed_d[pd1];
        const unsigned wr0 = packed_r[pr0];
        const unsigned wr1 = packed_r[pr1];
        atomicOr(&bits[pd0 >> 5], 1u << (pd0 & 31));
        atomicOr(&bits[pd1 >> 5], 1u << (pd1 & 31));
        atomicAdd(&lhist[              (wd0       & 255u)], 1u);
        atomicAdd(&lhist[1 * BINS + ((wd0 >> 8)  & 255u)], 1u);
        atomicAdd(&lhist[2 * BINS + ((wd0 >> 16) & 255u)], 1u);
        atomicAdd(&lhist[              (wd1       & 255u)], 1u);
        atomicAdd(&lhist[1 * BINS + ((wd1 >> 8)  & 255u)], 1u);
        atomicAdd(&lhist[2 * BINS + ((wd1 >> 16) & 255u)], 1u);
        atomicAdd(&lhist[3 * BINS + ((wr0)       & 255u)], 1u);
        atomicAdd(&lhist[4 * BINS + ((wr0 >> 8)  & 255u)], 1u);
        atomicAdd(&lhist[5 * BINS + ((wr0 >> 16) & 255u)], 1u);
        atomicAdd(&lhist[3 * BINS + ((wr1)       & 255u)], 1u);
        atomicAdd(&lhist[4 * BINS + ((wr1 >> 8)  & 255u)], 1u);
        atomicAdd(&lhist[5 * BINS + ((wr1 >> 16) & 255u)], 1u);
    }
    __syncthreads();
    unsigned* h = hist + (blockIdx.x & (NCOPY - 1)) * (6 * BINS);
    for (int t = threadIdx.x; t < 6 * BINS; t += 256) {
        const unsigned v = lhist[t];
        if (v) atomicAdd(&h[t], v);
    }
}

// Fully-parallel CDF + transfer table:
//   integer wave scan (exact) -> parallel float divide -> binary-search interval.
__global__ __launch_bounds__(256) void table_kernel(
    const unsigned* __restrict__ hist, float* __restrict__ tables)
{
    __shared__ float cdf_d[3][BINS];
    __shared__ float cdf_r[3][BINS];
    __shared__ unsigned wsum[4];
    const int t = threadIdx.x;
    const int lane = t & 63;
    const int wid = t >> 6;

    for (int ch = 0; ch < 6; ch++) {
        unsigned x = 0;
#pragma unroll
        for (int cp = 0; cp < NCOPY; cp++) x += hist[cp * (6 * BINS) + ch * BINS + t];
        // wave-inclusive scan (64 lanes)
#pragma unroll
        for (int d = 1; d < 64; d <<= 1) {
            const unsigned y = __shfl_up(x, d, 64);
            if (lane >= d) x += y;
        }
        if (lane == 63) wsum[wid] = x;
        __syncthreads();
        unsigned prefix = 0;
        for (int w = 0; w < wid; w++) prefix += wsum[w];
        x += prefix;
        const float f = (float)x / 2000000.0f;   // exact int < 2^24, single rounding
        if (ch < 3) cdf_d[ch][t] = f;
        else        cdf_r[ch - 3][t] = f;
        __syncthreads();
    }

    for (int c = 0; c < 3; c++) {
        float out;
        if (t == 0)             out = 0.0f;
        else if (t == BINS - 1) out = 255.0f;
        else {
            const float v = cdf_d[c][t];
            const float* arr = cdf_r[c];
            // lower_bound: first k with arr[k] >= v  (arr[255] = 1.0 >= v always)
            int lo = 0, hi = 256;
            while (lo < hi) { const int mid = (lo + hi) >> 1; if (arr[mid] < v) lo = mid + 1; else hi = mid; }
            const int J0 = ((lo > 1) ? lo : 1) - 1;
            // upper_bound: first k with arr[k] > v
            int lo2 = 0, hi2 = 256;
            while (lo2 < hi2) { const int mid = (lo2 + hi2) >> 1; if (arr[mid] <= v) lo2 = mid + 1; else hi2 = mid; }
            const int J1 = ((lo2 - 1) < 254 ? (lo2 - 1) : 254);
            const bool found = (lo2 >= 1) && (J0 <= J1);
            out = found ? (float)(J0 + 1) : (float)t;
        }
        tables[c * BINS + t] = out;
    }
}

__global__ __launch_bounds__(256) void loss_kernel(
    const float* __restrict__ inp, const float* __restrict__ ref,
    const float* __restrict__ msrc, const float* __restrict__ tables_g,
    const unsigned* __restrict__ bits, double* __restrict__ acc)
{
    __shared__ float tab[3 * BINS];
    for (int t = threadIdx.x; t < 3 * BINS; t += 256) tab[t] = tables_g[t];
    __syncthreads();

    double local = 0.0;
    const int ngroups = 3 * HH / 4;   // float4 groups
    const int stride = gridDim.x * 256;
    for (int g = blockIdx.x * 256 + threadIdx.x; g < ngroups; g += stride) {
        const int c = g / (HH / 4);
        const int p = (g - c * (HH / 4)) * 4;
        const float4 rv = *(const float4*)(ref + c * HH + p);
        const float4 iv = *(const float4*)(inp + c * HH + p);
        const float4 mv = *(const float4*)(msrc + p);
        const unsigned w = bits[p >> 5] >> (p & 31);  // p % 4 == 0, bits never cross a word
        const float r[4] = {rv.x, rv.y, rv.z, rv.w};
        const float x[4] = {iv.x, iv.y, iv.z, iv.w};
        const float m[4] = {mv.x, mv.y, mv.z, mv.w};
        float s = 0.0f;
#pragma unroll
        for (int k = 0; k < 4; k++) {
            const float mm = m[k];
            const float refm = ((r[k] + 1.0f) * 0.5f) * 255.0f * mm;   // ref_masked
            const float inpm = ((x[k] + 1.0f) * 0.5f) * 255.0f * mm;   // input_masked
            float matchv;
            if ((w >> k) & 1u) {
                const int bidx = (int)fminf(fmaxf(refm, 0.0f), 255.0f); // clip then trunc (ref semantics)
                matchv = tab[c * BINS + bidx];
            } else {
                matchv = refm;
            }
            const float d = inpm - matchv * mm;
            s += d * d;
        }
        local += (double)s;
    }

    __shared__ double red[256];
    red[threadIdx.x] = local;
    __syncthreads();
    for (int s2 = 128; s2 > 0; s2 >>= 1) {
        if (threadIdx.x < s2) red[threadIdx.x] += red[threadIdx.x + s2];
        __syncthreads();
    }
    if (threadIdx.x == 0) atomicAdd(acc, red[0]);
}

__global__ void finalize_kernel(const double* __restrict__ acc, float* __restrict__ out)
{
    out[0] = (float)(acc[0] / (double)(3 * HH));
}

extern "C" void kernel_launch(void* const* d_in, const int* in_sizes, int n_in,
                              void* d_out, int out_size, void* d_ws, size_t ws_size,
                              hipStream_t stream)
{
    const float* input_data  = (const float*)d_in[0];
    const float* target_data = (const float*)d_in[1];
    const float* mask_src    = (const float*)d_in[2];
    const float* mask_tar    = (const float*)d_in[3];
    const int*   i0          = (const int*)d_in[4];
    const int*   i1          = (const int*)d_in[5];
    const int*   i2          = (const int*)d_in[6];
    const int*   i3          = (const int*)d_in[7];
    const float* ref_data    = (const float*)d_in[8];
    float* out = (float*)d_out;

    char* ws = (char*)d_ws;
    double*   acc      = (double*)(ws + ACC_OFF);
    unsigned* hist     = (unsigned*)(ws + HIST_OFF);
    float*    tables   = (float*)(ws + TAB_OFF);
    unsigned* bits     = (unsigned*)(ws + BITS_OFF);
    unsigned* packed_d = (unsigned*)(ws + PACKED_D_OFF);
    unsigned* packed_r = (unsigned*)(ws + PACKED_R_OFF);

    hipMemsetAsync(ws, 0, WS_ZERO_BYTES, stream);
    pack_kernel<<<2048, 256, 0, stream>>>(ref_data, target_data, mask_src, mask_tar,
                                          packed_d, packed_r);
    hist_kernel<<<2048, 256, 0, stream>>>(packed_d, packed_r, i0, i1, i2, i3, hist, bits);
    table_kernel<<<1, 256, 0, stream>>>(hist, tables);
    loss_kernel<<<4096, 256, 0, stream>>>(input_data, ref_data, mask_src, tables, bits, acc);
    finalize_kernel<<<1, 1, 0, stream>>>(acc, out);
}